// Round 9
// baseline (177.572 us; speedup 1.0000x reference)
//
#include <hip/hip_runtime.h>
#include <math.h>

// Problem constants
#define T_DIM 8192
#define N_DIM 4096
#define L 64
#define P 32
#define IN_DIM 192
#define S_CHUNK 16
#define N_CHUNK (T_DIM / S_CHUNK)   // 512
#define LDST 68                     // padded LDS row stride (float4-aligned)

using f32x4   = __attribute__((ext_vector_type(4))) float;
using bf16x8  = __attribute__((ext_vector_type(8))) short;
using ushort8 = __attribute__((ext_vector_type(8))) unsigned short;

__device__ __forceinline__ unsigned short f2bf(float x) {
  unsigned u = __float_as_uint(x);
  u += 0x7fffu + ((u >> 16) & 1u);           // round-to-nearest-even
  return (unsigned short)(u >> 16);
}
__device__ __forceinline__ float bf2f(unsigned short h) {
  return __uint_as_float(((unsigned)h) << 16);
}

// Packed fragment layout (both X and U):
//   pk[tile16][g][lane] = 8 bf16 of row (tile16*16 + lane), k-chunk g
//   g in 0..15: g<8 -> hi bits of k=8g..; g>=8 -> lo residual.
__device__ __forceinline__ bf16x8 ldfrag(const unsigned short* __restrict__ base,
                                         int tile16, int gb, int lg, int lr) {
  return *(const bf16x8*)(base + ((size_t)((tile16 * 16 + gb + lg) * 16 + lr)) * 8);
}

// ---------------- kernel A (merged): xh0 partials + U split + scratch init ----------------
__global__ __launch_bounds__(256) void k_init(const float* __restrict__ U,
                                              const float* __restrict__ Xtr,
                                              float* __restrict__ part,
                                              double* __restrict__ acc,
                                              int* __restrict__ cnt,
                                              unsigned short* __restrict__ upk) {
  int blk = blockIdx.x, tid = threadIdx.x;
  if (blk < 16) {
    // xh0 partials: virtual block b = blk*4 + (tid>>6), 64 lanes each
    if (blk == 0) {
      if (tid < 2) acc[tid] = 0.0;
      if (tid == 2) *cnt = 0;
    }
    int b = blk * 4 + (tid >> 6);
    int l = tid & 63;
    int n0 = b * 64;
    float s = 0.f;
    #pragma unroll 8
    for (int i = 0; i < 64; ++i) {
      float x = Xtr[n0 + i];
      s += U[(size_t)(n0 + i) * L + l] * x;
    }
    part[b * 64 + l] = s;
  } else {
    // U split into packed fragments
    int idx = (blk - 16) * 256 + tid;         // 0 .. 65535
    int lr = idx & 15, g = (idx >> 4) & 15, nn16 = idx >> 8;
    int n = nn16 * 16 + lr;
    int k0 = (g & 7) * 8;
    float4 a = *(const float4*)(U + (size_t)n * L + k0);
    float4 b = *(const float4*)(U + (size_t)n * L + k0 + 4);
    ushort8 o;
    float v[8] = {a.x, a.y, a.z, a.w, b.x, b.y, b.z, b.w};
    #pragma unroll
    for (int j = 0; j < 8; ++j) {
      unsigned short h = f2bf(v[j]);
      o[j] = (g < 8) ? h : f2bf(v[j] - bf2f(h));
    }
    *(ushort8*)(upk + (size_t)idx * 8) = o;
  }
}

// ---------------- kernel B: argmax, temp, build M, xh0, matrix doublings ----------------
__global__ __launch_bounds__(256, 1) void k_prep(const float* __restrict__ A_tilde,
                                                 const float* __restrict__ phi_bar_t,
                                                 const float* __restrict__ logits,
                                                 const float* __restrict__ temp,
                                                 const float* __restrict__ part,
                                                 float* __restrict__ Wm,
                                                 float* __restrict__ xh0,
                                                 float* __restrict__ out_tail) {
  __shared__ float buf[2][64 * LDST];   // 34816 B
  __shared__ float sphi[P * L];         // 8192 B
  __shared__ float spart[4 * 64];       // 1024 B
  __shared__ int   sel_s[P];
  int tid = threadIdx.x;

  #pragma unroll
  for (int i = 0; i < 4; ++i) {
    int f = tid + 256 * i;
    int r = f >> 4, q = f & 15;
    float4 v = ((const float4*)A_tilde)[f];
    *(float4*)(buf[0] + r * LDST + q * 4) = v;
  }
  #pragma unroll
  for (int i = 0; i < 2; ++i) {
    int f = tid + 256 * i;
    ((float4*)sphi)[f] = ((const float4*)phi_bar_t)[f];
  }
  {
    int l = tid & 63, q = tid >> 6;
    float s = 0.f;
    #pragma unroll
    for (int i = 0; i < 16; ++i)
      s += part[(q * 16 + i) * 64 + l];
    spart[q * 64 + l] = s;
  }
  {
    int p = tid >> 3, d = tid & 7;
    const float* row = logits + p * IN_DIM;
    float best = -1e30f; int bk = 0;
    #pragma unroll
    for (int j = 0; j < 6; ++j) {
      int kb = (j * 8 + d) * 4;
      float4 v = *(const float4*)(row + kb);
      if (v.x > best) { best = v.x; bk = kb; }
      if (v.y > best) { best = v.y; bk = kb + 1; }
      if (v.z > best) { best = v.z; bk = kb + 2; }
      if (v.w > best) { best = v.w; bk = kb + 3; }
    }
    #pragma unroll
    for (int off = 4; off > 0; off >>= 1) {
      float vo = __shfl_down(best, off, 8);
      int   ko = __shfl_down(bk,   off, 8);
      if (vo > best || (vo == best && ko < bk)) { best = vo; bk = ko; }
    }
    if (d == 0) {
      sel_s[p] = bk;
      out_tail[2 + p] = (float)bk;
    }
  }
  if (tid == 255) out_tail[1] = fmaxf(0.01f, temp[0] * 0.999f);
  __syncthreads();

  if (tid < L) {
    #pragma unroll 4
    for (int p = 0; p < P; ++p) {
      int kk = sel_s[p]; if (kk > L - 1) kk = L - 1;
      buf[0][tid * LDST + kk] += sphi[p * L + tid];
    }
  } else if (tid < 128) {
    int l = tid - 64;
    xh0[l] = spart[l] + spart[64 + l] + spart[128 + l] + spart[192 + l];
  }
  __syncthreads();

  #pragma unroll
  for (int i = 0; i < 4; ++i) {
    int f = tid + 256 * i;
    int r = f >> 4, q = f & 15;
    *(float4*)(Wm + r * 64 + q * 4) = *(const float4*)(buf[0] + r * LDST + q * 4);
  }

  int r0 = (tid >> 4) << 2;
  int c0 = (tid & 15) << 2;
  int cur = 0;
  for (int j = 1; j <= 12; ++j) {
    const float* S = buf[cur];
    float* D = buf[cur ^ 1];
    float acc[4][4];
    #pragma unroll
    for (int i = 0; i < 4; ++i)
      #pragma unroll
      for (int c = 0; c < 4; ++c) acc[i][c] = 0.f;

    #pragma unroll
    for (int kb = 0; kb < 64; kb += 16) {
      float a[4][16];
      #pragma unroll
      for (int i = 0; i < 4; ++i)
        #pragma unroll
        for (int q = 0; q < 4; ++q) {
          float4 t4 = *(const float4*)(S + (r0 + i) * LDST + kb + q * 4);
          a[i][q * 4 + 0] = t4.x; a[i][q * 4 + 1] = t4.y;
          a[i][q * 4 + 2] = t4.z; a[i][q * 4 + 3] = t4.w;
        }
      #pragma unroll
      for (int kk = 0; kk < 16; ++kk) {
        float4 b4 = *(const float4*)(S + (kb + kk) * LDST + c0);
        #pragma unroll
        for (int i = 0; i < 4; ++i) {
          acc[i][0] += a[i][kk] * b4.x;
          acc[i][1] += a[i][kk] * b4.y;
          acc[i][2] += a[i][kk] * b4.z;
          acc[i][3] += a[i][kk] * b4.w;
        }
      }
    }
    #pragma unroll
    for (int i = 0; i < 4; ++i) {
      float4 o = {acc[i][0], acc[i][1], acc[i][2], acc[i][3]};
      *(float4*)(D + (r0 + i) * LDST + c0) = o;
      *(float4*)(Wm + j * 4096 + (r0 + i) * 64 + c0) = o;
    }
    __syncthreads();
    cur ^= 1;
  }
}

// ---------------- kernel C: states via checkpoints; emit PACKED bf16 hi/lo frags ----------------
__global__ __launch_bounds__(64) void k_states(const float* __restrict__ Wm,
                                               const float* __restrict__ xh0,
                                               unsigned short* __restrict__ xpk) {
  __shared__ float sx[16 * LDST];
  int c = blockIdx.x;
  int l = threadIdx.x;
  float v = xh0[l];
  int e = c << 4;
  for (int j = 4; j <= 12; ++j) {
    if ((e >> j) & 1) {
      const float* W = Wm + j * 4096;
      float n0 = 0.f, n1 = 0.f, n2 = 0.f, n3 = 0.f;
      #pragma unroll
      for (int k = 0; k < 64; k += 4) {
        n0 += W[l * 64 + k]     * __shfl(v, k, 64);
        n1 += W[l * 64 + k + 1] * __shfl(v, k + 1, 64);
        n2 += W[l * 64 + k + 2] * __shfl(v, k + 2, 64);
        n3 += W[l * 64 + k + 3] * __shfl(v, k + 3, 64);
      }
      v = (n0 + n1) + (n2 + n3);
    }
  }
  float m[64];
  #pragma unroll
  for (int k = 0; k < 64; ++k) m[k] = Wm[l * 64 + k];
  for (int i = 0; i < S_CHUNK; ++i) {
    float n0 = 0.f, n1 = 0.f, n2 = 0.f, n3 = 0.f;
    #pragma unroll
    for (int k = 0; k < 64; k += 4) {
      n0 += m[k]     * __shfl(v, k, 64);
      n1 += m[k + 1] * __shfl(v, k + 1, 64);
      n2 += m[k + 2] * __shfl(v, k + 2, 64);
      n3 += m[k + 3] * __shfl(v, k + 3, 64);
    }
    v = (n0 + n1) + (n2 + n3);
    sx[i * LDST + l] = v;
  }
  __syncthreads();

  #pragma unroll
  for (int it = 0; it < 4; ++it) {
    int idx = l + 64 * it;
    int lr = idx & 15, g = idx >> 4;
    int k0 = (g & 7) * 8;
    float4 a = *(const float4*)(sx + lr * LDST + k0);
    float4 b = *(const float4*)(sx + lr * LDST + k0 + 4);
    float vv[8] = {a.x, a.y, a.z, a.w, b.x, b.y, b.z, b.w};
    ushort8 o;
    #pragma unroll
    for (int j = 0; j < 8; ++j) {
      unsigned short h = f2bf(vv[j]);
      o[j] = (g < 8) ? h : f2bf(vv[j] - bf2f(h));
    }
    *(ushort8*)(xpk + ((size_t)c * 256 + idx) * 8) = o;
  }
}

// ---------------- kernel D: X_rec, STREAMING-shaped MFMA GEMM, fused err + finalize ----------------
// 1024 blocks x (16 t-rows x 2048 n): block sweeps n sequentially so Y/Xrec
// are read/written as 16 contiguous 8-KB spans (round-8 lesson: 512-B chunks
// at 16-KB stride across ~2000 blocks pinned HBM at 2.5 TB/s). XCD-chunked
// bijective swizzle gives each XCD a contiguous t-slab. X frags loop-invariant;
// U frags stream from L2 (upk 1 MiB resident). Plain stores (nt regressed).
__global__ __launch_bounds__(256, 4) void k_xrec(const unsigned short* __restrict__ xpk,
                                                 const unsigned short* __restrict__ upk,
                                                 const float* __restrict__ Y,
                                                 float* __restrict__ Xrec,
                                                 double* __restrict__ acc_g,
                                                 int* __restrict__ cnt,
                                                 float* __restrict__ out_tail) {
  __shared__ float red[512];
  int tid = threadIdx.x;
  int raw = blockIdx.x;                    // 1024 wgs, 8 XCDs, 128/XCD
  int wg = (raw & 7) * 128 + (raw >> 3);   // bijective chunked swizzle
  int th = wg >> 1;                        // t-stripe 0..511
  int nh = wg & 1;                         // n half
  int t0 = th * 16;
  int l = tid & 63, w = tid >> 6;
  int lr = l & 15, lg = l >> 4;
  int nwb = nh * 2048 + w * 512;           // wave n base

  // persistent X frags (tile16 == th)
  bf16x8 a_hi0 = ldfrag(xpk, th, 0,  lg, lr);
  bf16x8 a_hi1 = ldfrag(xpk, th, 4,  lg, lr);
  bf16x8 a_lo0 = ldfrag(xpk, th, 8,  lg, lr);
  bf16x8 a_lo1 = ldfrag(xpk, th, 12, lg, lr);

  float sd = 0.f, sy = 0.f;
  int t = t0 + lr;
  // 16 iterations x 2 n-frags (32 n per iter); n sweeps 512 per wave
  for (int g = 0; g < 16; ++g) {
    int nf0 = (nwb >> 4) + g * 2;
    bf16x8 u00 = ldfrag(upk, nf0,     0,  lg, lr);
    bf16x8 u01 = ldfrag(upk, nf0,     4,  lg, lr);
    bf16x8 u02 = ldfrag(upk, nf0,     8,  lg, lr);
    bf16x8 u03 = ldfrag(upk, nf0,     12, lg, lr);
    bf16x8 u10 = ldfrag(upk, nf0 + 1, 0,  lg, lr);
    bf16x8 u11 = ldfrag(upk, nf0 + 1, 4,  lg, lr);
    bf16x8 u12 = ldfrag(upk, nf0 + 1, 8,  lg, lr);
    bf16x8 u13 = ldfrag(upk, nf0 + 1, 12, lg, lr);

    size_t idx = (size_t)t * N_DIM + nwb + g * 32 + lg * 4;
    float4 y0 = *(const float4*)(Y + idx);
    float4 y1 = *(const float4*)(Y + idx + 16);

    f32x4 acc0 = (f32x4){0.f, 0.f, 0.f, 0.f};
    f32x4 acc1 = (f32x4){0.f, 0.f, 0.f, 0.f};
    acc0 = __builtin_amdgcn_mfma_f32_16x16x32_bf16(u00, a_hi0, acc0, 0, 0, 0);
    acc1 = __builtin_amdgcn_mfma_f32_16x16x32_bf16(u10, a_hi0, acc1, 0, 0, 0);
    acc0 = __builtin_amdgcn_mfma_f32_16x16x32_bf16(u01, a_hi1, acc0, 0, 0, 0);
    acc1 = __builtin_amdgcn_mfma_f32_16x16x32_bf16(u11, a_hi1, acc1, 0, 0, 0);
    acc0 = __builtin_amdgcn_mfma_f32_16x16x32_bf16(u00, a_lo0, acc0, 0, 0, 0);
    acc1 = __builtin_amdgcn_mfma_f32_16x16x32_bf16(u10, a_lo0, acc1, 0, 0, 0);
    acc0 = __builtin_amdgcn_mfma_f32_16x16x32_bf16(u01, a_lo1, acc0, 0, 0, 0);
    acc1 = __builtin_amdgcn_mfma_f32_16x16x32_bf16(u11, a_lo1, acc1, 0, 0, 0);
    acc0 = __builtin_amdgcn_mfma_f32_16x16x32_bf16(u02, a_hi0, acc0, 0, 0, 0);
    acc1 = __builtin_amdgcn_mfma_f32_16x16x32_bf16(u12, a_hi0, acc1, 0, 0, 0);
    acc0 = __builtin_amdgcn_mfma_f32_16x16x32_bf16(u03, a_hi1, acc0, 0, 0, 0);
    acc1 = __builtin_amdgcn_mfma_f32_16x16x32_bf16(u13, a_hi1, acc1, 0, 0, 0);

    float d;
    d = y0.x - acc0[0]; sd += d * d; sy += y0.x * y0.x;
    d = y0.y - acc0[1]; sd += d * d; sy += y0.y * y0.y;
    d = y0.z - acc0[2]; sd += d * d; sy += y0.z * y0.z;
    d = y0.w - acc0[3]; sd += d * d; sy += y0.w * y0.w;
    d = y1.x - acc1[0]; sd += d * d; sy += y1.x * y1.x;
    d = y1.y - acc1[1]; sd += d * d; sy += y1.y * y1.y;
    d = y1.z - acc1[2]; sd += d * d; sy += y1.z * y1.z;
    d = y1.w - acc1[3]; sd += d * d; sy += y1.w * y1.w;
    *(f32x4*)(Xrec + idx) = acc0;
    *(f32x4*)(Xrec + idx + 16) = acc1;
  }

  red[tid] = sd; red[256 + tid] = sy;
  __syncthreads();
  for (int s2 = 128; s2 > 0; s2 >>= 1) {
    if (tid < s2) { red[tid] += red[tid + s2]; red[256 + tid] += red[256 + tid + s2]; }
    __syncthreads();
  }
  if (tid == 0) {
    atomicAdd(acc_g,     (double)red[0]);
    atomicAdd(acc_g + 1, (double)red[256]);
    __threadfence();
    int done = atomicAdd(cnt, 1);
    if (done == 1023) {                       // last block finalizes err
      double s0 = atomicAdd(acc_g, 0.0);
      double s1 = atomicAdd(acc_g + 1, 0.0);
      out_tail[0] = (float)sqrt(s0 / s1);
    }
  }
}

extern "C" void kernel_launch(void* const* d_in, const int* in_sizes, int n_in,
                              void* d_out, int out_size, void* d_ws, size_t ws_size,
                              hipStream_t stream) {
  const float* X_train = (const float*)d_in[1];
  const float* Y       = (const float*)d_in[2];
  const float* temp    = (const float*)d_in[3];
  const float* phi     = (const float*)d_in[4];
  const float* A_tilde = (const float*)d_in[5];
  const float* U       = (const float*)d_in[6];
  const float* logits  = (const float*)d_in[7];
  float* out = (float*)d_out;
  float* out_tail = out + (size_t)T_DIM * N_DIM;

  // workspace layout (bytes)
  char* w = (char*)d_ws;
  double* acc          = (double*)w;                     // @0, 16 B
  int* cnt             = (int*)(w + 32);                 // 4 B
  float* Wm            = (float*)(w + 64);               // 13*16384 B -> ends 213056
  float* xh0           = (float*)(w + 213056);           // 256 B
  float* part          = (float*)(w + 213312);           // 16384 B -> ends 229696
  unsigned short* upk  = (unsigned short*)(w + 262144);  // 1 MiB packed U frags
  unsigned short* xpk  = (unsigned short*)(w + 1310720); // 2 MiB packed X frags -> ends 3407872

  k_init<<<272, 256, 0, stream>>>(U, X_train, part, acc, cnt, upk);
  k_prep<<<1, 256, 0, stream>>>(A_tilde, phi, logits, temp, part, Wm, xh0, out_tail);
  k_states<<<N_CHUNK, 64, 0, stream>>>(Wm, xh0, xpk);
  k_xrec<<<1024, 256, 0, stream>>>(xpk, upk, Y, out, acc, cnt, out_tail);
}